// Round 5
// baseline (366.634 us; speedup 1.0000x reference)
//
#include <hip/hip_runtime.h>
#include <math.h>

#define BB 2
#define CIN 256
#define COUT 128
#define LL 4096
#define DI 256
#define DS 16

#define SC_T 8      // chunk length (== k_mid tile)
#define SC_NC 512   // chunks per batch
#define XCP 257     // sxc LDS pitch (conflict-free)

__device__ __forceinline__ float silu_(float x){ return x / (1.f + expf(-x)); }
__device__ __forceinline__ float sigm_(float x){ return 1.f / (1.f + expf(-x)); }

// ---------- W_eff[p][c][o] = sum_i w_up[c,i,p>>1,p&1] * w_fuse[i,o] ----------
__global__ __launch_bounds__(256) void k_weff(const float* __restrict__ w_up,
                       const float* __restrict__ w_fuse, float* __restrict__ W_eff){
  int idx = blockIdx.x * 256 + threadIdx.x;   // 4*256*128
  int o = idx & 127;
  int c = (idx >> 7) & 255;
  int p = idx >> 15;
  int kh = p >> 1, kw = p & 1;
  float acc = 0.f;
  #pragma unroll 8
  for (int i = 0; i < COUT; ++i)
    acc += w_up[((c * COUT + i) * 2 + kh) * 2 + kw] * w_fuse[i * COUT + o];
  W_eff[idx] = acc;
}

// ---------- weight prep: transposes + m_WxT (k-major) + Aexp ----------
__global__ __launch_bounds__(256) void k_tr_all(
    const float* __restrict__ gW_in, const float* __restrict__ gW_gate,
    const float* __restrict__ gW_out, const float* __restrict__ m_Win,
    const float* __restrict__ m_Wout, const float* __restrict__ m_Wx,
    const float* __restrict__ m_Alog,
    float* __restrict__ gW_inT, float* __restrict__ gW_gateT,
    float* __restrict__ gW_outT, float* __restrict__ m_WinT,
    float* __restrict__ m_WoutT, float* __restrict__ m_WxT,
    float* __restrict__ Aexp){
  int idx = blockIdx.x * 256 + threadIdx.x;   // 161792 total
  if (idx < 16384){ int r = idx >> 7, c = idx & 127; gW_inT[c * 128 + r] = gW_in[idx]; }
  else if (idx < 32768){ int i = idx - 16384; int r = i >> 7, c = i & 127; gW_gateT[c * 128 + r] = gW_gate[i]; }
  else if (idx < 49152){ int i = idx - 32768; int r = i >> 7, c = i & 127; gW_outT[c * 128 + r] = gW_out[i]; }
  else if (idx < 114688){ int i = idx - 49152; int r = i >> 7, c = i & 127; m_WinT[c * 512 + r] = m_Win[i]; }
  else if (idx < 147456){ int i = idx - 114688; int r = i >> 8, c = i & 255; m_WoutT[c * 128 + r] = m_Wout[i]; }
  else if (idx < 157696){ int i = idx - 147456; int o = i >> 8, k = i & 255; m_WxT[k * 40 + o] = m_Wx[i]; }
  else if (idx < 161792){ int i = idx - 157696; Aexp[i] = -expf(m_Alog[i]); }
}

// ---------- fused tokens (8-px tile, grid 1024) + partial stats ----------
__global__ __launch_bounds__(256) void k_fused(const float* __restrict__ inp,
                        const float* __restrict__ skip,
                        const float* __restrict__ W_eff, const float* __restrict__ w_fuse,
                        float* __restrict__ fusedT, float* __restrict__ partials1){
  int bid = blockIdx.x;            // b*512 + h*8 + wt
  int wt = bid & 7;
  int h  = (bid >> 3) & 63;
  int b  = bid >> 9;
  int t  = threadIdx.x;            // 256
  int o  = t & 127;
  int wp = t >> 7;                 // 0/1 -> 4 pixels each

  __shared__ float sIn[256 * 4];   // [c][wl<4]
  __shared__ float sSk[128 * 8];   // [i][wl2<8]
  int hi = h >> 1;
  int wi0 = wt * 4;
  #pragma unroll
  for (int k = 0; k < 4; ++k){
    int e = k * 256 + t;
    int c = e >> 2, wl = e & 3;
    sIn[e] = inp[((b * 256 + c) * 32 + hi) * 32 + wi0 + wl];
  }
  #pragma unroll
  for (int k = 0; k < 4; ++k){
    int e = k * 256 + t;
    int i = e >> 3, wl2 = e & 7;
    sSk[e] = skip[((b * 128 + i) * 64 + h) * 64 + wt * 8 + wl2];
  }
  __syncthreads();

  float acc[4];
  #pragma unroll
  for (int j = 0; j < 4; ++j) acc[j] = 0.f;

  for (int par = 0; par < 2; ++par){
    int p = (h & 1) * 2 + par;
    const float* wptr = W_eff + (size_t)p * 256 * 128 + o;
    for (int c = 0; c < 256; ++c){
      float we = wptr[c * 128];
      acc[par]     += sIn[c * 4 + wp * 2 + 0] * we;   // px_local = par
      acc[2 + par] += sIn[c * 4 + wp * 2 + 1] * we;   // px_local = 2+par
    }
  }
  for (int i = 0; i < 128; ++i){
    float wf = w_fuse[(128 + i) * 128 + o];
    #pragma unroll
    for (int j = 0; j < 4; ++j)
      acc[j] += sSk[i * 8 + wp * 4 + j] * wf;
  }
  float s4 = 0.f, q4 = 0.f;
  #pragma unroll
  for (int j = 0; j < 4; ++j){
    int w = wt * 8 + wp * 4 + j;
    fusedT[((size_t)(b * 4096 + h * 64 + w)) * 128 + o] = acc[j];
    s4 += acc[j]; q4 += acc[j] * acc[j];
  }
  __shared__ float sS[256], sQ[256];
  sS[t] = s4; sQ[t] = q4;
  __syncthreads();
  if (t < 128){
    partials1[(size_t)bid * 256 + t * 2]     = sS[t] + sS[t + 128];
    partials1[(size_t)bid * 256 + t * 2 + 1] = sQ[t] + sQ[t + 128];
  }
}

// ---------- reduce partials -> mu, rs (grid=2, 256 thr) ----------
__global__ __launch_bounds__(256) void k_stats2(const float* __restrict__ partials, int nb,
                         float cnt, float* __restrict__ mu, float* __restrict__ rs){
  int b = blockIdx.x;
  int t = threadIdx.x;
  int c = t & 127, half = t >> 7;
  int n2 = nb >> 1;
  float S = 0.f, Q = 0.f;
  for (int k = half * n2; k < (half + 1) * n2; ++k){
    S += partials[(size_t)(b * nb + k) * 256 + c * 2];
    Q += partials[(size_t)(b * nb + k) * 256 + c * 2 + 1];
  }
  __shared__ float sS[256], sQ[256];
  sS[t] = S; sQ[t] = Q;
  __syncthreads();
  if (t < 128){
    float Sa = sS[t] + sS[t + 128], Qa = sQ[t] + sQ[t + 128];
    float m = Sa / cnt;
    mu[b * 128 + t] = m;
    rs[b * 128 + t] = rsqrtf(Qa / cnt - m * m + 1e-5f);
  }
}

// ---------- front: norm+leaky -> (tok2, z) -> LN -> xz GEMM -> xm, zs ----------
__global__ __launch_bounds__(256) void k_front(const float* __restrict__ xt,
                      const float* __restrict__ mu1, const float* __restrict__ rs1,
                      const float* __restrict__ gW_inT, const float* __restrict__ gW_gateT,
                      const float* __restrict__ gb_gate,
                      const float* __restrict__ ln_g, const float* __restrict__ ln_b,
                      const float* __restrict__ m_WinT,
                      float* __restrict__ tok2, float* __restrict__ zb,
                      float* __restrict__ xm, float* __restrict__ zs){
  int tok0 = blockIdx.x * 8;
  int b = tok0 >> 12;
  int t = threadIdx.x;
  __shared__ float xn[128 * 8];    // [c][tok]
  __shared__ float tn[128 * 8];
  __shared__ float aT[8 * 132];    // [tok][o]
  __shared__ float sMu[8], sRs[8];

  #pragma unroll
  for (int k = 0; k < 4; ++k){
    int e = k * 256 + t;
    int tok = e >> 7, c = e & 127;
    float v = xt[(size_t)(tok0 + tok) * 128 + c];
    v = (v - mu1[b * 128 + c]) * rs1[b * 128 + c];
    v = v >= 0.f ? v : 0.01f * v;
    xn[c * 8 + tok] = v;
  }
  __syncthreads();

  int o = t & 127, th = t >> 7;
  float accA[4], accG[4];
  #pragma unroll
  for (int j = 0; j < 4; ++j){ accA[j] = 0.f; accG[j] = 0.f; }
  for (int c = 0; c < 128; ++c){
    float wa = gW_inT[c * 128 + o];
    float wg = gW_gateT[c * 128 + o];
    float4 x = *(const float4*)&xn[c * 8 + th * 4];
    accA[0] += x.x * wa; accA[1] += x.y * wa; accA[2] += x.z * wa; accA[3] += x.w * wa;
    accG[0] += x.x * wg; accG[1] += x.y * wg; accG[2] += x.z * wg; accG[3] += x.w * wg;
  }
  float gb = gb_gate[o];
  #pragma unroll
  for (int j = 0; j < 4; ++j){
    int tok = th * 4 + j;
    tok2[(size_t)(tok0 + tok) * 128 + o] = accA[j];
    zb[(size_t)(tok0 + tok) * 128 + o] = sigm_(silu_(accG[j] + gb));
    aT[tok * 132 + o] = accA[j];
  }
  __syncthreads();

  if (t < 128){
    int tok = t >> 4, i = t & 15;
    float s = 0.f, q = 0.f;
    #pragma unroll
    for (int j = 0; j < 8; ++j){ float a = aT[tok * 132 + i * 8 + j]; s += a; q += a * a; }
    s += __shfl_down(s, 8, 16); q += __shfl_down(q, 8, 16);
    s += __shfl_down(s, 4, 16); q += __shfl_down(q, 4, 16);
    s += __shfl_down(s, 2, 16); q += __shfl_down(q, 2, 16);
    s += __shfl_down(s, 1, 16); q += __shfl_down(q, 1, 16);
    if (i == 0){
      float m = s / 128.f;
      sMu[tok] = m;
      sRs[tok] = rsqrtf(q / 128.f - m * m + 1e-5f);
    }
  }
  __syncthreads();
  #pragma unroll
  for (int k = 0; k < 4; ++k){
    int e = k * 256 + t;
    int tok = e >> 7, c = e & 127;
    tn[c * 8 + tok] = (aT[tok * 132 + c] - sMu[tok]) * sRs[tok] * ln_g[c] + ln_b[c];
  }
  __syncthreads();

  float a0[8], a1[8];
  #pragma unroll
  for (int j = 0; j < 8; ++j){ a0[j] = 0.f; a1[j] = 0.f; }
  for (int c = 0; c < 128; ++c){
    float w0 = m_WinT[c * 512 + t];
    float w1 = m_WinT[c * 512 + 256 + t];
    float4 x0 = *(const float4*)&tn[c * 8];
    float4 x1 = *(const float4*)&tn[c * 8 + 4];
    a0[0] += x0.x * w0; a0[1] += x0.y * w0; a0[2] += x0.z * w0; a0[3] += x0.w * w0;
    a0[4] += x1.x * w0; a0[5] += x1.y * w0; a0[6] += x1.z * w0; a0[7] += x1.w * w0;
    a1[0] += x0.x * w1; a1[1] += x0.y * w1; a1[2] += x0.z * w1; a1[3] += x0.w * w1;
    a1[4] += x1.x * w1; a1[5] += x1.y * w1; a1[6] += x1.z * w1; a1[7] += x1.w * w1;
  }
  #pragma unroll
  for (int j = 0; j < 8; ++j){
    xm[(size_t)(tok0 + j) * 256 + t] = a0[j];
    zs[(size_t)(tok0 + j) * 256 + t] = silu_(a1[j]);
  }
}

// ---------- mid: conv+silu -> x_dbl -> dt/B/C -> local scan (SC_T=8, grid 1024) ----------
__global__ __launch_bounds__(256) void k_mid(const float* __restrict__ xm,
                    const float* __restrict__ cw, const float* __restrict__ cb,
                    const float* __restrict__ m_WxT, const float* __restrict__ m_Wdt,
                    const float* __restrict__ m_bdt, const float* __restrict__ Aexp,
                    float* __restrict__ xcb, float* __restrict__ dtb,
                    float* __restrict__ Bmb, float* __restrict__ Cmb,
                    float* __restrict__ chunkA, float* __restrict__ chunkH){
  int ch = blockIdx.x & (SC_NC - 1), b = blockIdx.x >> 9;
  int l0 = ch * SC_T;
  int tok0 = b * LL + l0;          // global token index
  int t = threadIdx.x;
  __shared__ float sxm[11 * 256];
  __shared__ float sxc[8 * XCP];
  __shared__ float sdbl[8 * 40];

  #pragma unroll
  for (int r = 0; r < 11; ++r){
    int l = l0 - 3 + r;
    sxm[r * 256 + t] = (l >= 0) ? xm[(size_t)(b * LL + l) * 256 + t] : 0.f;
  }
  __syncthreads();

  // conv (thread = d)
  float cw0 = cw[t * 4], cw1 = cw[t * 4 + 1], cw2 = cw[t * 4 + 2], cw3 = cw[t * 4 + 3];
  float cbv = cb[t];
  float xcr[8];
  #pragma unroll
  for (int j = 0; j < 8; ++j){
    float a = cbv + sxm[j * 256 + t] * cw0 + sxm[(j + 1) * 256 + t] * cw1
                  + sxm[(j + 2) * 256 + t] * cw2 + sxm[(j + 3) * 256 + t] * cw3;
    a = silu_(a);
    xcr[j] = a;
    sxc[j * XCP + t] = a;
    xcb[(size_t)(tok0 + j) * 256 + t] = a;
  }
  __syncthreads();

  // x_dbl: thread = (tok=t>>5, i=t&31): output 8+i; i<8 also output i
  {
    int tok = t >> 5, i = t & 31;
    float acc = 0.f, acc0 = 0.f;
    const float* xcrow = &sxc[tok * XCP];
    const float* wcol = &m_WxT[8 + i];
    for (int k = 0; k < 256; ++k){
      float xv = xcrow[k];
      acc += xv * wcol[k * 40];
      if (i < 8) acc0 += xv * m_WxT[k * 40 + i];
    }
    sdbl[tok * 40 + 8 + i] = acc;
    if (i < 8) sdbl[tok * 40 + i] = acc0;
    if (i < 16) Bmb[(size_t)(tok0 + tok) * 16 + i] = acc;
    else        Cmb[(size_t)(tok0 + tok) * 16 + (i - 16)] = acc;
  }
  __syncthreads();

  // dt + local scan (thread = d)
  float w8[8];
  #pragma unroll
  for (int r = 0; r < 8; ++r) w8[r] = m_Wdt[t * 8 + r];
  float bdt = m_bdt[t];
  float A[16];
  {
    const float4* ap = (const float4*)&Aexp[t * 16];
    float4 a0 = ap[0], a1 = ap[1], a2 = ap[2], a3 = ap[3];
    A[0]=a0.x; A[1]=a0.y; A[2]=a0.z; A[3]=a0.w;
    A[4]=a1.x; A[5]=a1.y; A[6]=a1.z; A[7]=a1.w;
    A[8]=a2.x; A[9]=a2.y; A[10]=a2.z; A[11]=a2.w;
    A[12]=a3.x; A[13]=a3.y; A[14]=a3.z; A[15]=a3.w;
  }
  float h[16];
  #pragma unroll
  for (int s = 0; s < 16; ++s) h[s] = 0.f;
  float sumdt = 0.f;
  #pragma unroll 2
  for (int j = 0; j < 8; ++j){
    float dtr = bdt;
    #pragma unroll
    for (int r = 0; r < 8; ++r) dtr += sdbl[j * 40 + r] * w8[r];
    float dt = (dtr > 20.f) ? dtr : log1pf(expf(dtr));
    dtb[(size_t)(tok0 + j) * 256 + t] = dt;
    sumdt += dt;
    float u = dt * xcr[j];
    const float4* bp = (const float4*)&sdbl[j * 40 + 8];
    float4 b0 = bp[0], b1 = bp[1], b2 = bp[2], b3 = bp[3];
    float bv[16] = {b0.x,b0.y,b0.z,b0.w, b1.x,b1.y,b1.z,b1.w,
                    b2.x,b2.y,b2.z,b2.w, b3.x,b3.y,b3.z,b3.w};
    #pragma unroll
    for (int s = 0; s < 16; ++s)
      h[s] = expf(dt * A[s]) * h[s] + u * bv[s];
  }
  size_t base = ((size_t)(b * SC_NC + ch)) * 4096 + t * 16;
  #pragma unroll
  for (int s = 0; s < 16; ++s){
    chunkA[base + s] = expf(A[s] * sumdt);
    chunkH[base + s] = h[s];
  }
}

// ---------- scanB: serial combine; carry written IN PLACE into chunkH ----------
__global__ __launch_bounds__(256) void k_scanB(const float* __restrict__ chunkA,
                        float* __restrict__ chunkH){
  int gid = blockIdx.x * 256 + threadIdx.x;  // 8192
  int ds = gid & 4095;
  int b = gid >> 12;
  size_t base = (size_t)b * SC_NC * 4096 + ds;
  float carry = 0.f;
  for (int c = 0; c < SC_NC; c += 4){
    size_t i0 = base + (size_t)c * 4096;
    float A0 = chunkA[i0],         H0 = chunkH[i0];
    float A1 = chunkA[i0 + 4096],  H1 = chunkH[i0 + 4096];
    float A2 = chunkA[i0 + 8192],  H2 = chunkH[i0 + 8192];
    float A3 = chunkA[i0 + 12288], H3 = chunkH[i0 + 12288];
    chunkH[i0] = carry;           carry = A0 * carry + H0;
    chunkH[i0 + 4096] = carry;    carry = A1 * carry + H1;
    chunkH[i0 + 8192] = carry;    carry = A2 * carry + H2;
    chunkH[i0 + 12288] = carry;   carry = A3 * carry + H3;
  }
}

// ---------- back: re-scan + y -> mout GEMM -> gate -> out proj -> residual + IN2 stats ----------
__global__ __launch_bounds__(256) void k_back(const float* __restrict__ dtb,
                        const float* __restrict__ xcb,
                        const float* __restrict__ Bmb, const float* __restrict__ Cmb,
                        const float* __restrict__ Aexp, const float* __restrict__ m_D,
                        const float* __restrict__ zs, const float* __restrict__ carryBuf,
                        const float* __restrict__ m_WoutT,
                        const float* __restrict__ zb, const float* __restrict__ gW_outT,
                        const float* __restrict__ xt, const float* __restrict__ tok2,
                        const float* __restrict__ mu1, const float* __restrict__ rs1,
                        float* __restrict__ outpre, float* __restrict__ partials2){
  int ch = blockIdx.x & (SC_NC - 1), b = blockIdx.x >> 9;
  int l0 = ch * SC_T;
  int tok0 = b * LL + l0;
  int t = threadIdx.x;
  __shared__ float sB[SC_T * 16], sC[SC_T * 16];
  __shared__ float yT[8 * 256];    // [l][d]
  __shared__ float sv[8 * 128];    // [tok][c]
  __shared__ float sS[256], sQ[256];
  if (t < 128){
    sB[t] = Bmb[(size_t)tok0 * 16 + t];
    sC[t] = Cmb[(size_t)tok0 * 16 + t];
  }
  __syncthreads();

  // scan phase (thread = d)
  float A[16], h[16];
  {
    const float4* ap = (const float4*)&Aexp[t * 16];
    float4 a0 = ap[0], a1 = ap[1], a2 = ap[2], a3 = ap[3];
    A[0]=a0.x; A[1]=a0.y; A[2]=a0.z; A[3]=a0.w;
    A[4]=a1.x; A[5]=a1.y; A[6]=a1.z; A[7]=a1.w;
    A[8]=a2.x; A[9]=a2.y; A[10]=a2.z; A[11]=a2.w;
    A[12]=a3.x; A[13]=a3.y; A[14]=a3.z; A[15]=a3.w;
  }
  size_t cbase = ((size_t)(b * SC_NC + ch)) * 4096 + t * 16;
  {
    const float4* cp = (const float4*)&carryBuf[cbase];
    float4 c0 = cp[0], c1 = cp[1], c2 = cp[2], c3 = cp[3];
    h[0]=c0.x; h[1]=c0.y; h[2]=c0.z; h[3]=c0.w;
    h[4]=c1.x; h[5]=c1.y; h[6]=c1.z; h[7]=c1.w;
    h[8]=c2.x; h[9]=c2.y; h[10]=c2.z; h[11]=c2.w;
    h[12]=c3.x; h[13]=c3.y; h[14]=c3.z; h[15]=c3.w;
  }
  float Dv = m_D[t];
  const float* dtp = dtb + (size_t)tok0 * 256 + t;
  const float* xcp = xcb + (size_t)tok0 * 256 + t;
  const float* zp  = zs  + (size_t)tok0 * 256 + t;
  #pragma unroll 2
  for (int l = 0; l < SC_T; ++l){
    float dt = dtp[l * 256];
    float xc = xcp[l * 256];
    float zv = zp[l * 256];
    float u = dt * xc;
    const float4* bp = (const float4*)&sB[l * 16];
    const float4* cp = (const float4*)&sC[l * 16];
    float4 b0 = bp[0], b1 = bp[1], b2 = bp[2], b3 = bp[3];
    float4 c0 = cp[0], c1 = cp[1], c2 = cp[2], c3 = cp[3];
    float bv[16] = {b0.x,b0.y,b0.z,b0.w, b1.x,b1.y,b1.z,b1.w,
                    b2.x,b2.y,b2.z,b2.w, b3.x,b3.y,b3.z,b3.w};
    float cv[16] = {c0.x,c0.y,c0.z,c0.w, c1.x,c1.y,c1.z,c1.w,
                    c2.x,c2.y,c2.z,c2.w, c3.x,c3.y,c3.z,c3.w};
    float y = 0.f;
    #pragma unroll
    for (int s = 0; s < 16; ++s){
      h[s] = expf(dt * A[s]) * h[s] + u * bv[s];
      y += h[s] * cv[s];
    }
    yT[l * 256 + t] = (y + xc * Dv) * zv;   // stride-1 write, conflict-free
  }
  __syncthreads();

  // mout GEMM: thread (cc=t&127, th=t>>7), 4 toks each
  int cc = t & 127, th = t >> 7;
  float acc[4];
  #pragma unroll
  for (int j = 0; j < 4; ++j) acc[j] = 0.f;
  for (int dd = 0; dd < 256; ++dd){
    float w = m_WoutT[dd * 128 + cc];
    acc[0] += yT[(th * 4 + 0) * 256 + dd] * w;
    acc[1] += yT[(th * 4 + 1) * 256 + dd] * w;
    acc[2] += yT[(th * 4 + 2) * 256 + dd] * w;
    acc[3] += yT[(th * 4 + 3) * 256 + dd] * w;
  }
  #pragma unroll
  for (int j = 0; j < 4; ++j){
    int tok = th * 4 + j;
    float z = zb[(size_t)(tok0 + tok) * 128 + cc];
    sv[tok * 128 + cc] = acc[j] * z;
  }
  __syncthreads();

  // out proj GEMM
  float acc2[4];
  #pragma unroll
  for (int j = 0; j < 4; ++j) acc2[j] = 0.f;
  for (int ci = 0; ci < 128; ++ci){
    float w = gW_outT[ci * 128 + cc];
    acc2[0] += sv[(th * 4 + 0) * 128 + ci] * w;
    acc2[1] += sv[(th * 4 + 1) * 128 + ci] * w;
    acc2[2] += sv[(th * 4 + 2) * 128 + ci] * w;
    acc2[3] += sv[(th * 4 + 3) * 128 + ci] * w;
  }
  float mu = mu1[b * 128 + cc], rsg = rs1[b * 128 + cc];
  float ps = 0.f, pq = 0.f;
  #pragma unroll
  for (int j = 0; j < 4; ++j){
    size_t idx = (size_t)(tok0 + th * 4 + j) * 128 + cc;
    float x = xt[idx];
    float xn = (x - mu) * rsg;
    xn = xn >= 0.f ? xn : 0.01f * xn;
    float v = xn + tok2[idx] + acc2[j];
    outpre[idx] = v;
    ps += v; pq += v * v;
  }
  sS[t] = ps; sQ[t] = pq;
  __syncthreads();
  if (t < 128){
    partials2[(size_t)blockIdx.x * 256 + t * 2]     = sS[t] + sS[t + 128];
    partials2[(size_t)blockIdx.x * 256 + t * 2 + 1] = sQ[t] + sQ[t + 128];
  }
}

// ---------- final: instance-norm + NCHW transpose via LDS (grid 512) ----------
__global__ __launch_bounds__(256) void k_final(const float* __restrict__ outpre,
                        const float* __restrict__ mu,
                        const float* __restrict__ rs, float* __restrict__ out){
  int bid = blockIdx.x;            // b*256 + cg*128 + lg
  int lg = bid & 127, cg = (bid >> 7) & 1, b = bid >> 8;
  int t = threadIdx.x;
  __shared__ float sT[64 * 33];
  int l0 = lg * 32, c0 = cg * 64;
  #pragma unroll
  for (int k = 0; k < 8; ++k){
    int e = k * 256 + t;
    int l = e >> 6, cc = e & 63;
    float v = outpre[(size_t)(b * 4096 + l0 + l) * 128 + c0 + cc];
    v = (v - mu[b * 128 + c0 + cc]) * rs[b * 128 + c0 + cc];
    sT[cc * 33 + l] = v;
  }
  __syncthreads();
  #pragma unroll
  for (int k = 0; k < 8; ++k){
    int e = k * 256 + t;
    int cc = e >> 5, l = e & 31;
    out[((size_t)(b * 128 + c0 + cc)) * 4096 + l0 + l] = sT[cc * 33 + l];
  }
}

extern "C" void kernel_launch(void* const* d_in, const int* in_sizes, int n_in,
                              void* d_out, int out_size, void* d_ws, size_t ws_size,
                              hipStream_t stream){
  const float* inp    = (const float*)d_in[0];
  const float* skip   = (const float*)d_in[1];
  const float* w_up   = (const float*)d_in[2];
  const float* w_fuse = (const float*)d_in[3];
  const float* gW_in  = (const float*)d_in[4];
  const float* gW_gate= (const float*)d_in[5];
  const float* gb_gate= (const float*)d_in[6];
  const float* ln_g   = (const float*)d_in[7];
  const float* ln_b   = (const float*)d_in[8];
  const float* gW_out = (const float*)d_in[9];
  const float* m_Win  = (const float*)d_in[10];
  const float* m_convw= (const float*)d_in[11];
  const float* m_convb= (const float*)d_in[12];
  const float* m_Wx   = (const float*)d_in[13];
  const float* m_Wdt  = (const float*)d_in[14];
  const float* m_bdt  = (const float*)d_in[15];
  const float* m_Alog = (const float*)d_in[16];
  const float* m_D    = (const float*)d_in[17];
  const float* m_Wout = (const float*)d_in[18];
  float* out = (float*)d_out;

  float* ws = (float*)d_ws;
  float* W_eff    = ws;                        // 131072
  float* xt       = W_eff + 131072;            // 1048576
  float* tok2     = xt + 1048576;              // 1048576
  float* zb       = tok2 + 1048576;            // 1048576
  float* xmbuf    = zb + 1048576;              // 2097152 (xm, later outpre)
  float* zs       = xmbuf + 2097152;           // 2097152
  float* xcb      = zs + 2097152;              // 2097152
  float* dtb      = xcb + 2097152;             // 2097152
  float* Bmb      = dtb + 2097152;             // 131072
  float* Cmb      = Bmb + 131072;              // 131072
  float* chunkA   = Cmb + 131072;              // 4194304
  float* chunkH   = chunkA + 4194304;          // 4194304 (becomes carry in place)
  float* partials = chunkH + 4194304;          // 262144 (reused for IN1 and IN2)
  float* stats    = partials + 262144;         // 1024
  float* gW_inT   = stats + 1024;              // 16384
  float* gW_gateT = gW_inT + 16384;            // 16384
  float* gW_outT  = gW_gateT + 16384;          // 16384
  float* m_WinT   = gW_outT + 16384;           // 65536
  float* m_WoutT  = m_WinT + 65536;            // 32768
  float* m_WxT    = m_WoutT + 32768;           // 10240
  float* AexpBuf  = m_WxT + 10240;             // 4096

  float* mu1 = stats, *rs1 = stats + 256, *mu2 = stats + 512, *rs2 = stats + 768;
  float* xm = xmbuf;
  float* outpre = xmbuf;   // alias: xm dead after k_mid

  k_weff<<<512, 256, 0, stream>>>(w_up, w_fuse, W_eff);
  k_tr_all<<<632, 256, 0, stream>>>(gW_in, gW_gate, gW_out, m_Win, m_Wout, m_Wx, m_Alog,
                                    gW_inT, gW_gateT, gW_outT, m_WinT, m_WoutT, m_WxT,
                                    AexpBuf);

  k_fused<<<1024, 256, 0, stream>>>(inp, skip, W_eff, w_fuse, xt, partials);
  k_stats2<<<2, 256, 0, stream>>>(partials, 512, 4096.f, mu1, rs1);

  k_front<<<1024, 256, 0, stream>>>(xt, mu1, rs1, gW_inT, gW_gateT, gb_gate, ln_g, ln_b,
                                    m_WinT, tok2, zb, xm, zs);
  k_mid<<<1024, 256, 0, stream>>>(xm, m_convw, m_convb, m_WxT, m_Wdt, m_bdt, AexpBuf,
                                  xcb, dtb, Bmb, Cmb, chunkA, chunkH);
  k_scanB<<<32, 256, 0, stream>>>(chunkA, chunkH);
  k_back<<<1024, 256, 0, stream>>>(dtb, xcb, Bmb, Cmb, AexpBuf, m_D, zs, chunkH,
                                   m_WoutT, zb, gW_outT, xt, tok2, mu1, rs1,
                                   outpre, partials);
  k_stats2<<<2, 256, 0, stream>>>(partials, 512, 4096.f, mu2, rs2);
  k_final<<<512, 256, 0, stream>>>(outpre, mu2, rs2, out);
}

// Round 6
// 266.293 us; speedup vs baseline: 1.3768x; 1.3768x over previous
//
#include <hip/hip_runtime.h>
#include <math.h>

#define BB 2
#define CIN 256
#define COUT 128
#define LL 4096
#define DI 256
#define DS 16

#define SC_T 16     // chunk length (== k_mid tile)
#define SC_NC 256   // chunks per batch

__device__ __forceinline__ float silu_(float x){ return x / (1.f + expf(-x)); }
__device__ __forceinline__ float sigm_(float x){ return 1.f / (1.f + expf(-x)); }

// ---------- W_eff[p][c][o] = sum_i w_up[c,i,p>>1,p&1] * w_fuse[i,o] ----------
__global__ __launch_bounds__(256) void k_weff(const float* __restrict__ w_up,
                       const float* __restrict__ w_fuse, float* __restrict__ W_eff){
  int idx = blockIdx.x * 256 + threadIdx.x;   // 4*256*128
  int o = idx & 127;
  int c = (idx >> 7) & 255;
  int p = idx >> 15;
  int kh = p >> 1, kw = p & 1;
  float acc = 0.f;
  #pragma unroll 8
  for (int i = 0; i < COUT; ++i)
    acc += w_up[((c * COUT + i) * 2 + kh) * 2 + kw] * w_fuse[i * COUT + o];
  W_eff[idx] = acc;
}

// ---------- weight prep: transposes + Aexp ----------
__global__ __launch_bounds__(256) void k_tr_all(
    const float* __restrict__ gW_in, const float* __restrict__ gW_gate,
    const float* __restrict__ gW_out, const float* __restrict__ m_Win,
    const float* __restrict__ m_Wout, const float* __restrict__ m_Alog,
    float* __restrict__ gW_inT, float* __restrict__ gW_gateT,
    float* __restrict__ gW_outT, float* __restrict__ m_WinT,
    float* __restrict__ m_WoutT, float* __restrict__ Aexp){
  int idx = blockIdx.x * 256 + threadIdx.x;   // 151552 total
  if (idx < 16384){ int r = idx >> 7, c = idx & 127; gW_inT[c * 128 + r] = gW_in[idx]; }
  else if (idx < 32768){ int i = idx - 16384; int r = i >> 7, c = i & 127; gW_gateT[c * 128 + r] = gW_gate[i]; }
  else if (idx < 49152){ int i = idx - 32768; int r = i >> 7, c = i & 127; gW_outT[c * 128 + r] = gW_out[i]; }
  else if (idx < 114688){ int i = idx - 49152; int r = i >> 7, c = i & 127; m_WinT[c * 512 + r] = m_Win[i]; }
  else if (idx < 147456){ int i = idx - 114688; int r = i >> 8, c = i & 255; m_WoutT[c * 128 + r] = m_Wout[i]; }
  else if (idx < 151552){ int i = idx - 147456; Aexp[i] = -expf(m_Alog[i]); }
}

// ---------- fused tokens (16-px tile, grid 512) + partial stats ----------
__global__ __launch_bounds__(256) void k_fused(const float* __restrict__ inp,
                        const float* __restrict__ skip,
                        const float* __restrict__ W_eff, const float* __restrict__ w_fuse,
                        float* __restrict__ fusedT, float* __restrict__ partials1){
  int bid = blockIdx.x;            // b*256 + h*4 + wt
  int wt = bid & 3;
  int h  = (bid >> 2) & 63;
  int b  = bid >> 8;
  int t  = threadIdx.x;            // 256
  int o  = t & 127;
  int wp = t >> 7;

  __shared__ float sIn[256 * 8];
  __shared__ float sSk[128 * 16];
  int hi = h >> 1;
  int wi0 = wt * 8;
  #pragma unroll
  for (int k = 0; k < 8; ++k){
    int e = k * 256 + t;
    int c = e >> 3, wl = e & 7;
    sIn[e] = inp[((b * 256 + c) * 32 + hi) * 32 + wi0 + wl];
  }
  #pragma unroll
  for (int k = 0; k < 8; ++k){
    int e = k * 256 + t;
    int i = e >> 4, wl2 = e & 15;
    sSk[e] = skip[((b * 128 + i) * 64 + h) * 64 + wt * 16 + wl2];
  }
  __syncthreads();

  float acc[8];
  #pragma unroll
  for (int j = 0; j < 8; ++j) acc[j] = 0.f;

  for (int par = 0; par < 2; ++par){
    int p = (h & 1) * 2 + par;
    const float* wptr = W_eff + (size_t)p * 256 * 128 + o;
    for (int c = 0; c < 256; ++c){
      float we = wptr[c * 128];
      #pragma unroll
      for (int jj = 0; jj < 4; ++jj){
        int j = jj * 2 + par;
        int wl = (wp * 8 + j) >> 1;
        acc[j] += sIn[c * 8 + wl] * we;
      }
    }
  }
  for (int i = 0; i < 128; ++i){
    float wf = w_fuse[(128 + i) * 128 + o];
    #pragma unroll
    for (int j = 0; j < 8; ++j)
      acc[j] += sSk[i * 16 + wp * 8 + j] * wf;
  }
  float s8 = 0.f, q8 = 0.f;
  #pragma unroll
  for (int j = 0; j < 8; ++j){
    int w = wt * 16 + wp * 8 + j;
    fusedT[((size_t)(b * 4096 + h * 64 + w)) * 128 + o] = acc[j];
    s8 += acc[j]; q8 += acc[j] * acc[j];
  }
  __shared__ float sS[256], sQ[256];
  sS[t] = s8; sQ[t] = q8;
  __syncthreads();
  if (t < 128){
    partials1[(size_t)bid * 256 + t * 2]     = sS[t] + sS[t + 128];
    partials1[(size_t)bid * 256 + t * 2 + 1] = sQ[t] + sQ[t + 128];
  }
}

// ---------- reduce partials -> mu, rs (grid=2, 256 thr), nb per-batch blocks ----------
__global__ __launch_bounds__(256) void k_stats2(const float* __restrict__ partials, int nb,
                         float cnt, float* __restrict__ mu, float* __restrict__ rs){
  int b = blockIdx.x;
  int t = threadIdx.x;
  int c = t & 127, half = t >> 7;
  int n2 = nb >> 1;
  float S = 0.f, Q = 0.f;
  for (int k = half * n2; k < (half + 1) * n2; ++k){
    S += partials[(size_t)(b * nb + k) * 256 + c * 2];
    Q += partials[(size_t)(b * nb + k) * 256 + c * 2 + 1];
  }
  __shared__ float sS[256], sQ[256];
  sS[t] = S; sQ[t] = Q;
  __syncthreads();
  if (t < 128){
    float Sa = sS[t] + sS[t + 128], Qa = sQ[t] + sQ[t + 128];
    float m = Sa / cnt;
    mu[b * 128 + t] = m;
    rs[b * 128 + t] = rsqrtf(Qa / cnt - m * m + 1e-5f);
  }
}

// ---------- front: norm+leaky -> (tok2, z) -> LN -> xz GEMM -> xm, zs ----------
__global__ __launch_bounds__(256) void k_front(const float* __restrict__ xt,
                      const float* __restrict__ mu1, const float* __restrict__ rs1,
                      const float* __restrict__ gW_inT, const float* __restrict__ gW_gateT,
                      const float* __restrict__ gb_gate,
                      const float* __restrict__ ln_g, const float* __restrict__ ln_b,
                      const float* __restrict__ m_WinT,
                      float* __restrict__ tok2, float* __restrict__ zb,
                      float* __restrict__ xm, float* __restrict__ zs){
  int tok0 = blockIdx.x * 8;
  int b = tok0 >> 12;
  int t = threadIdx.x;
  __shared__ float xn[128 * 8];    // [c][tok]
  __shared__ float tn[128 * 8];
  __shared__ float aT[8 * 132];    // [tok][o]
  __shared__ float sMu[8], sRs[8];

  #pragma unroll
  for (int k = 0; k < 4; ++k){
    int e = k * 256 + t;
    int tok = e >> 7, c = e & 127;
    float v = xt[(size_t)(tok0 + tok) * 128 + c];
    v = (v - mu1[b * 128 + c]) * rs1[b * 128 + c];
    v = v >= 0.f ? v : 0.01f * v;
    xn[c * 8 + tok] = v;
  }
  __syncthreads();

  int o = t & 127, th = t >> 7;
  float accA[4], accG[4];
  #pragma unroll
  for (int j = 0; j < 4; ++j){ accA[j] = 0.f; accG[j] = 0.f; }
  for (int c = 0; c < 128; ++c){
    float wa = gW_inT[c * 128 + o];
    float wg = gW_gateT[c * 128 + o];
    float4 x = *(const float4*)&xn[c * 8 + th * 4];
    accA[0] += x.x * wa; accA[1] += x.y * wa; accA[2] += x.z * wa; accA[3] += x.w * wa;
    accG[0] += x.x * wg; accG[1] += x.y * wg; accG[2] += x.z * wg; accG[3] += x.w * wg;
  }
  float gb = gb_gate[o];
  #pragma unroll
  for (int j = 0; j < 4; ++j){
    int tok = th * 4 + j;
    tok2[(size_t)(tok0 + tok) * 128 + o] = accA[j];
    zb[(size_t)(tok0 + tok) * 128 + o] = sigm_(silu_(accG[j] + gb));
    aT[tok * 132 + o] = accA[j];
  }
  __syncthreads();

  if (t < 128){
    int tok = t >> 4, i = t & 15;
    float s = 0.f, q = 0.f;
    #pragma unroll
    for (int j = 0; j < 8; ++j){ float a = aT[tok * 132 + i * 8 + j]; s += a; q += a * a; }
    s += __shfl_down(s, 8, 16); q += __shfl_down(q, 8, 16);
    s += __shfl_down(s, 4, 16); q += __shfl_down(q, 4, 16);
    s += __shfl_down(s, 2, 16); q += __shfl_down(q, 2, 16);
    s += __shfl_down(s, 1, 16); q += __shfl_down(q, 1, 16);
    if (i == 0){
      float m = s / 128.f;
      sMu[tok] = m;
      sRs[tok] = rsqrtf(q / 128.f - m * m + 1e-5f);
    }
  }
  __syncthreads();
  #pragma unroll
  for (int k = 0; k < 4; ++k){
    int e = k * 256 + t;
    int tok = e >> 7, c = e & 127;
    tn[c * 8 + tok] = (aT[tok * 132 + c] - sMu[tok]) * sRs[tok] * ln_g[c] + ln_b[c];
  }
  __syncthreads();

  float a0[8], a1[8];
  #pragma unroll
  for (int j = 0; j < 8; ++j){ a0[j] = 0.f; a1[j] = 0.f; }
  for (int c = 0; c < 128; ++c){
    float w0 = m_WinT[c * 512 + t];
    float w1 = m_WinT[c * 512 + 256 + t];
    float4 x0 = *(const float4*)&tn[c * 8];
    float4 x1 = *(const float4*)&tn[c * 8 + 4];
    a0[0] += x0.x * w0; a0[1] += x0.y * w0; a0[2] += x0.z * w0; a0[3] += x0.w * w0;
    a0[4] += x1.x * w0; a0[5] += x1.y * w0; a0[6] += x1.z * w0; a0[7] += x1.w * w0;
    a1[0] += x0.x * w1; a1[1] += x0.y * w1; a1[2] += x0.z * w1; a1[3] += x0.w * w1;
    a1[4] += x1.x * w1; a1[5] += x1.y * w1; a1[6] += x1.z * w1; a1[7] += x1.w * w1;
  }
  #pragma unroll
  for (int j = 0; j < 8; ++j){
    xm[(size_t)(tok0 + j) * 256 + t] = a0[j];
    zs[(size_t)(tok0 + j) * 256 + t] = silu_(a1[j]);
  }
}

// ---------- mid: conv(regs) -> x_dbl(float4, 4-acc) -> dt -> local scan (SC_T=16, grid 512) ----------
__global__ __launch_bounds__(256) void k_mid(const float* __restrict__ xm,
                    const float* __restrict__ cw, const float* __restrict__ cb,
                    const float* __restrict__ m_Wx, const float* __restrict__ m_Wdt,
                    const float* __restrict__ m_bdt, const float* __restrict__ Aexp,
                    float* __restrict__ xcb, float* __restrict__ dtb,
                    float* __restrict__ Bmb, float* __restrict__ Cmb,
                    float* __restrict__ chunkA, float* __restrict__ chunkH){
  int ch = blockIdx.x & (SC_NC - 1), b = blockIdx.x >> 8;
  int l0 = ch * SC_T;
  int tok0 = b * LL + l0;
  int t = threadIdx.x;
  __shared__ float sxc[SC_T * 256];   // [tok][d]
  __shared__ float sdbl[SC_T * 40];

  // stage xm halo into registers (thread = d)
  float xr[SC_T + 3];
  #pragma unroll
  for (int r = 0; r < SC_T + 3; ++r){
    int l = l0 - 3 + r;
    xr[r] = (l >= 0) ? xm[(size_t)(b * LL + l) * 256 + t] : 0.f;
  }
  // conv + silu
  float4 cwv = *(const float4*)&cw[t * 4];
  float cbv = cb[t];
  float xcr[SC_T];
  #pragma unroll
  for (int j = 0; j < SC_T; ++j){
    float a = cbv + xr[j] * cwv.x + xr[j + 1] * cwv.y + xr[j + 2] * cwv.z + xr[j + 3] * cwv.w;
    a = silu_(a);
    xcr[j] = a;
    sxc[j * 256 + t] = a;
    xcb[(size_t)(tok0 + j) * 256 + t] = a;
  }
  __syncthreads();

  // x_dbl B/C: thread = (tokHalf loop, tok = half*8 + t>>5, i = t&31), out 8+i
  {
    int i = t & 31, th = t >> 5;
    const float4* wrow = (const float4*)&m_Wx[(8 + i) * 256];
    #pragma unroll
    for (int half = 0; half < 2; ++half){
      int tok = half * 8 + th;
      const float4* xrow = (const float4*)&sxc[tok * 256];
      float a0 = 0.f, a1 = 0.f, a2 = 0.f, a3 = 0.f;
      #pragma unroll 8
      for (int k = 0; k < 64; ++k){
        float4 w = wrow[k];
        float4 x = xrow[k];
        a0 += x.x * w.x; a1 += x.y * w.y; a2 += x.z * w.z; a3 += x.w * w.w;
      }
      float a = (a0 + a1) + (a2 + a3);
      sdbl[tok * 40 + 8 + i] = a;
      if (i < 16) Bmb[(size_t)(tok0 + tok) * 16 + i] = a;
      else        Cmb[(size_t)(tok0 + tok) * 16 + (i - 16)] = a;
    }
  }
  // x_dbl dt-rank: threads t<128: tok = t>>3, i = t&7
  if (t < 128){
    int tok = t >> 3, i = t & 7;
    const float4* wrow = (const float4*)&m_Wx[i * 256];
    const float4* xrow = (const float4*)&sxc[tok * 256];
    float a0 = 0.f, a1 = 0.f, a2 = 0.f, a3 = 0.f;
    #pragma unroll 8
    for (int k = 0; k < 64; ++k){
      float4 w = wrow[k];
      float4 x = xrow[k];
      a0 += x.x * w.x; a1 += x.y * w.y; a2 += x.z * w.z; a3 += x.w * w.w;
    }
    sdbl[tok * 40 + i] = (a0 + a1) + (a2 + a3);
  }
  __syncthreads();

  // dt + local scan (thread = d)
  float4 wd0 = *(const float4*)&m_Wdt[t * 8];
  float4 wd1 = *(const float4*)&m_Wdt[t * 8 + 4];
  float bdt = m_bdt[t];
  float A[16];
  {
    const float4* ap = (const float4*)&Aexp[t * 16];
    float4 q0 = ap[0], q1 = ap[1], q2 = ap[2], q3 = ap[3];
    A[0]=q0.x; A[1]=q0.y; A[2]=q0.z; A[3]=q0.w;
    A[4]=q1.x; A[5]=q1.y; A[6]=q1.z; A[7]=q1.w;
    A[8]=q2.x; A[9]=q2.y; A[10]=q2.z; A[11]=q2.w;
    A[12]=q3.x; A[13]=q3.y; A[14]=q3.z; A[15]=q3.w;
  }
  float h[16];
  #pragma unroll
  for (int s = 0; s < 16; ++s) h[s] = 0.f;
  float sumdt = 0.f;
  #pragma unroll 2
  for (int j = 0; j < SC_T; ++j){
    const float4* dp = (const float4*)&sdbl[j * 40];
    float4 d0 = dp[0], d1 = dp[1];
    float dtr = bdt + d0.x * wd0.x + d0.y * wd0.y + d0.z * wd0.z + d0.w * wd0.w
                    + d1.x * wd1.x + d1.y * wd1.y + d1.z * wd1.z + d1.w * wd1.w;
    float dt = (dtr > 20.f) ? dtr : log1pf(expf(dtr));
    dtb[(size_t)(tok0 + j) * 256 + t] = dt;
    sumdt += dt;
    float u = dt * xcr[j];
    const float4* bp = (const float4*)&sdbl[j * 40 + 8];
    float4 b0 = bp[0], b1 = bp[1], b2 = bp[2], b3 = bp[3];
    float bv[16] = {b0.x,b0.y,b0.z,b0.w, b1.x,b1.y,b1.z,b1.w,
                    b2.x,b2.y,b2.z,b2.w, b3.x,b3.y,b3.z,b3.w};
    #pragma unroll
    for (int s = 0; s < 16; ++s)
      h[s] = expf(dt * A[s]) * h[s] + u * bv[s];
  }
  size_t base = ((size_t)(b * SC_NC + ch)) * 4096 + t * 16;
  float4* cAp = (float4*)&chunkA[base];
  float4* cHp = (float4*)&chunkH[base];
  #pragma unroll
  for (int q = 0; q < 4; ++q){
    float4 va, vh;
    va.x = expf(A[q*4+0] * sumdt); va.y = expf(A[q*4+1] * sumdt);
    va.z = expf(A[q*4+2] * sumdt); va.w = expf(A[q*4+3] * sumdt);
    vh.x = h[q*4+0]; vh.y = h[q*4+1]; vh.z = h[q*4+2]; vh.w = h[q*4+3];
    cAp[q] = va; cHp[q] = vh;
  }
}

// ---------- scanB: serial combine; carry written IN PLACE into chunkH ----------
__global__ __launch_bounds__(256) void k_scanB(const float* __restrict__ chunkA,
                        float* __restrict__ chunkH){
  int gid = blockIdx.x * 256 + threadIdx.x;  // 8192
  int ds = gid & 4095;
  int b = gid >> 12;
  size_t base = (size_t)b * SC_NC * 4096 + ds;
  float carry = 0.f;
  for (int c = 0; c < SC_NC; c += 8){
    size_t i0 = base + (size_t)c * 4096;
    float Av[8], Hv[8];
    #pragma unroll
    for (int q = 0; q < 8; ++q){ Av[q] = chunkA[i0 + (size_t)q * 4096]; Hv[q] = chunkH[i0 + (size_t)q * 4096]; }
    #pragma unroll
    for (int q = 0; q < 8; ++q){
      chunkH[i0 + (size_t)q * 4096] = carry;
      carry = Av[q] * carry + Hv[q];
    }
  }
}

// ---------- back: re-scan + y -> mout GEMM -> gate -> out proj -> residual + IN2 stats ----------
// 512 threads, grid 512 (SC_T=16)
__global__ __launch_bounds__(512) void k_back(const float* __restrict__ dtb,
                        const float* __restrict__ xcb,
                        const float* __restrict__ Bmb, const float* __restrict__ Cmb,
                        const float* __restrict__ Aexp, const float* __restrict__ m_D,
                        const float* __restrict__ zs, const float* __restrict__ carryBuf,
                        const float* __restrict__ m_WoutT,
                        const float* __restrict__ zb, const float* __restrict__ gW_outT,
                        const float* __restrict__ xt, const float* __restrict__ tok2,
                        const float* __restrict__ mu1, const float* __restrict__ rs1,
                        float* __restrict__ outpre, float* __restrict__ partials2){
  int ch = blockIdx.x & (SC_NC - 1), b = blockIdx.x >> 8;
  int l0 = ch * SC_T;
  int tok0 = b * LL + l0;
  int t = threadIdx.x;
  __shared__ float sB[SC_T * 16], sC[SC_T * 16];
  __shared__ float yT[SC_T * 256];    // [l][d]
  __shared__ float sv[SC_T * 128];    // [tok][c]
  __shared__ float sS[512], sQ[512];
  if (t < 256){
    sB[t] = Bmb[(size_t)tok0 * 16 + t];
    sC[t] = Cmb[(size_t)tok0 * 16 + t];
  }
  __syncthreads();

  if (t < 256){
    float A[16], h[16];
    {
      const float4* ap = (const float4*)&Aexp[t * 16];
      float4 q0 = ap[0], q1 = ap[1], q2 = ap[2], q3 = ap[3];
      A[0]=q0.x; A[1]=q0.y; A[2]=q0.z; A[3]=q0.w;
      A[4]=q1.x; A[5]=q1.y; A[6]=q1.z; A[7]=q1.w;
      A[8]=q2.x; A[9]=q2.y; A[10]=q2.z; A[11]=q2.w;
      A[12]=q3.x; A[13]=q3.y; A[14]=q3.z; A[15]=q3.w;
    }
    size_t cbase = ((size_t)(b * SC_NC + ch)) * 4096 + t * 16;
    {
      const float4* cp = (const float4*)&carryBuf[cbase];
      float4 c0 = cp[0], c1 = cp[1], c2 = cp[2], c3 = cp[3];
      h[0]=c0.x; h[1]=c0.y; h[2]=c0.z; h[3]=c0.w;
      h[4]=c1.x; h[5]=c1.y; h[6]=c1.z; h[7]=c1.w;
      h[8]=c2.x; h[9]=c2.y; h[10]=c2.z; h[11]=c2.w;
      h[12]=c3.x; h[13]=c3.y; h[14]=c3.z; h[15]=c3.w;
    }
    float Dv = m_D[t];
    const float* dtp = dtb + (size_t)tok0 * 256 + t;
    const float* xcp = xcb + (size_t)tok0 * 256 + t;
    const float* zp  = zs  + (size_t)tok0 * 256 + t;
    #pragma unroll 2
    for (int l = 0; l < SC_T; ++l){
      float dt = dtp[l * 256];
      float xc = xcp[l * 256];
      float zv = zp[l * 256];
      float u = dt * xc;
      const float4* bp = (const float4*)&sB[l * 16];
      const float4* cp = (const float4*)&sC[l * 16];
      float4 b0 = bp[0], b1 = bp[1], b2 = bp[2], b3 = bp[3];
      float4 c0 = cp[0], c1 = cp[1], c2 = cp[2], c3 = cp[3];
      float bv[16] = {b0.x,b0.y,b0.z,b0.w, b1.x,b1.y,b1.z,b1.w,
                      b2.x,b2.y,b2.z,b2.w, b3.x,b3.y,b3.z,b3.w};
      float cv[16] = {c0.x,c0.y,c0.z,c0.w, c1.x,c1.y,c1.z,c1.w,
                      c2.x,c2.y,c2.z,c2.w, c3.x,c3.y,c3.z,c3.w};
      float y = 0.f;
      #pragma unroll
      for (int s = 0; s < 16; ++s){
        h[s] = expf(dt * A[s]) * h[s] + u * bv[s];
        y += h[s] * cv[s];
      }
      yT[l * 256 + t] = (y + xc * Dv) * zv;
    }
  }
  __syncthreads();

  // mout GEMM: all 512 threads, cc = t&127, th = t>>7 (0..3): toks th*4..+3
  int cc = t & 127, th = t >> 7;
  float acc[4];
  #pragma unroll
  for (int j = 0; j < 4; ++j) acc[j] = 0.f;
  for (int dd = 0; dd < 256; ++dd){
    float w = m_WoutT[dd * 128 + cc];
    acc[0] += yT[(th * 4 + 0) * 256 + dd] * w;
    acc[1] += yT[(th * 4 + 1) * 256 + dd] * w;
    acc[2] += yT[(th * 4 + 2) * 256 + dd] * w;
    acc[3] += yT[(th * 4 + 3) * 256 + dd] * w;
  }
  #pragma unroll
  for (int j = 0; j < 4; ++j){
    int tok = th * 4 + j;
    float z = zb[(size_t)(tok0 + tok) * 128 + cc];
    sv[tok * 128 + cc] = acc[j] * z;
  }
  __syncthreads();

  // out proj GEMM
  float acc2[4];
  #pragma unroll
  for (int j = 0; j < 4; ++j) acc2[j] = 0.f;
  for (int ci = 0; ci < 128; ++ci){
    float w = gW_outT[ci * 128 + cc];
    acc2[0] += sv[(th * 4 + 0) * 128 + ci] * w;
    acc2[1] += sv[(th * 4 + 1) * 128 + ci] * w;
    acc2[2] += sv[(th * 4 + 2) * 128 + ci] * w;
    acc2[3] += sv[(th * 4 + 3) * 128 + ci] * w;
  }
  float mu = mu1[b * 128 + cc], rsg = rs1[b * 128 + cc];
  float ps = 0.f, pq = 0.f;
  #pragma unroll
  for (int j = 0; j < 4; ++j){
    size_t idx = (size_t)(tok0 + th * 4 + j) * 128 + cc;
    float x = xt[idx];
    float xn = (x - mu) * rsg;
    xn = xn >= 0.f ? xn : 0.01f * xn;
    float v = xn + tok2[idx] + acc2[j];
    outpre[idx] = v;
    ps += v; pq += v * v;
  }
  sS[t] = ps; sQ[t] = pq;
  __syncthreads();
  if (t < 128){
    partials2[(size_t)blockIdx.x * 256 + t * 2]     = sS[t] + sS[t + 128] + sS[t + 256] + sS[t + 384];
    partials2[(size_t)blockIdx.x * 256 + t * 2 + 1] = sQ[t] + sQ[t + 128] + sQ[t + 256] + sQ[t + 384];
  }
}

// ---------- final: instance-norm + NCHW transpose via LDS (grid 512) ----------
__global__ __launch_bounds__(256) void k_final(const float* __restrict__ outpre,
                        const float* __restrict__ mu,
                        const float* __restrict__ rs, float* __restrict__ out){
  int bid = blockIdx.x;            // b*256 + cg*128 + lg
  int lg = bid & 127, cg = (bid >> 7) & 1, b = bid >> 8;
  int t = threadIdx.x;
  __shared__ float sT[64 * 33];
  int l0 = lg * 32, c0 = cg * 64;
  #pragma unroll
  for (int k = 0; k < 8; ++k){
    int e = k * 256 + t;
    int l = e >> 6, cc = e & 63;
    float v = outpre[(size_t)(b * 4096 + l0 + l) * 128 + c0 + cc];
    v = (v - mu[b * 128 + c0 + cc]) * rs[b * 128 + c0 + cc];
    sT[cc * 33 + l] = v;
  }
  __syncthreads();
  #pragma unroll
  for (int k = 0; k < 8; ++k){
    int e = k * 256 + t;
    int cc = e >> 5, l = e & 31;
    out[((size_t)(b * 128 + c0 + cc)) * 4096 + l0 + l] = sT[cc * 33 + l];
  }
}

extern "C" void kernel_launch(void* const* d_in, const int* in_sizes, int n_in,
                              void* d_out, int out_size, void* d_ws, size_t ws_size,
                              hipStream_t stream){
  const float* inp    = (const float*)d_in[0];
  const float* skip   = (const float*)d_in[1];
  const float* w_up   = (const float*)d_in[2];
  const float* w_fuse = (const float*)d_in[3];
  const float* gW_in  = (const float*)d_in[4];
  const float* gW_gate= (const float*)d_in[5];
  const float* gb_gate= (const float*)d_in[6];
  const float* ln_g   = (const float*)d_in[7];
  const float* ln_b   = (const float*)d_in[8];
  const float* gW_out = (const float*)d_in[9];
  const float* m_Win  = (const float*)d_in[10];
  const float* m_convw= (const float*)d_in[11];
  const float* m_convb= (const float*)d_in[12];
  const float* m_Wx   = (const float*)d_in[13];
  const float* m_Wdt  = (const float*)d_in[14];
  const float* m_bdt  = (const float*)d_in[15];
  const float* m_Alog = (const float*)d_in[16];
  const float* m_D    = (const float*)d_in[17];
  const float* m_Wout = (const float*)d_in[18];
  float* out = (float*)d_out;

  float* ws = (float*)d_ws;
  float* W_eff    = ws;                        // 131072
  float* xt       = W_eff + 131072;            // 1048576
  float* tok2     = xt + 1048576;              // 1048576
  float* zb       = tok2 + 1048576;            // 1048576
  float* xmbuf    = zb + 1048576;              // 2097152 (xm, later outpre)
  float* zs       = xmbuf + 2097152;           // 2097152
  float* xcb      = zs + 2097152;              // 2097152
  float* dtb      = xcb + 2097152;             // 2097152
  float* Bmb      = dtb + 2097152;             // 131072
  float* Cmb      = Bmb + 131072;              // 131072
  float* chunkA   = Cmb + 131072;              // 2097152
  float* chunkH   = chunkA + 2097152;          // 2097152 (carry in place)
  float* partials = chunkH + 2097152;          // 131072 (IN1, reused IN2)
  float* stats    = partials + 131072;         // 1024
  float* gW_inT   = stats + 1024;              // 16384
  float* gW_gateT = gW_inT + 16384;            // 16384
  float* gW_outT  = gW_gateT + 16384;          // 16384
  float* m_WinT   = gW_outT + 16384;           // 65536
  float* m_WoutT  = m_WinT + 65536;            // 32768
  float* AexpBuf  = m_WoutT + 32768;           // 4096

  float* mu1 = stats, *rs1 = stats + 256, *mu2 = stats + 512, *rs2 = stats + 768;
  float* xm = xmbuf;
  float* outpre = xmbuf;   // alias: xm dead after k_mid

  k_weff<<<512, 256, 0, stream>>>(w_up, w_fuse, W_eff);
  k_tr_all<<<592, 256, 0, stream>>>(gW_in, gW_gate, gW_out, m_Win, m_Wout, m_Alog,
                                    gW_inT, gW_gateT, gW_outT, m_WinT, m_WoutT, AexpBuf);

  k_fused<<<512, 256, 0, stream>>>(inp, skip, W_eff, w_fuse, xt, partials);
  k_stats2<<<2, 256, 0, stream>>>(partials, 256, 4096.f, mu1, rs1);

  k_front<<<1024, 256, 0, stream>>>(xt, mu1, rs1, gW_inT, gW_gateT, gb_gate, ln_g, ln_b,
                                    m_WinT, tok2, zb, xm, zs);
  k_mid<<<512, 256, 0, stream>>>(xm, m_convw, m_convb, m_Wx, m_Wdt, m_bdt, AexpBuf,
                                 xcb, dtb, Bmb, Cmb, chunkA, chunkH);
  k_scanB<<<32, 256, 0, stream>>>(chunkA, chunkH);
  k_back<<<512, 512, 0, stream>>>(dtb, xcb, Bmb, Cmb, AexpBuf, m_D, zs, chunkH,
                                  m_WoutT, zb, gW_outT, xt, tok2, mu1, rs1,
                                  outpre, partials);
  k_stats2<<<2, 256, 0, stream>>>(partials, 256, 4096.f, mu2, rs2);
  k_final<<<512, 256, 0, stream>>>(outpre, mu2, rs2, out);
}